// Round 2
// baseline (624.737 us; speedup 1.0000x reference)
//
#include <hip/hip_runtime.h>

// ObsBCELoss: per-(batch,column) gumbel log-softmax NLL at target index.
// B=4096, N_COLS=64, BIN=256, TAU=1.0. Output: [loss, loss/(B*ln2)].
//
// Only the target-index log-softmax value is needed per segment:
//   contribution = (lse - z[t]) if mask[t]==0 else 0
// where z = logits + gumbel over the 256-element contiguous segment.
//
// NOTE: harness uploads the numpy bool mask as int32 (all integer inputs
// become const int*). Round-1 failure was exactly the 7/4 loss inflation
// predicted by reading it as bytes.

#define BIN 256

__global__ __launch_bounds__(256) void obs_loss_kernel(
    const float* __restrict__ logits,
    const float* __restrict__ gumbel,
    const int* __restrict__ mask,      // numpy bool uploaded as int32
    const int* __restrict__ targets,
    float* __restrict__ out,
    int n_segs)
{
    const int lane = threadIdx.x & 63;
    const int waveInBlock = threadIdx.x >> 6;
    const int wavesPerBlock = blockDim.x >> 6;
    const int waveGid = blockIdx.x * wavesPerBlock + waveInBlock;
    const int totalWaves = gridDim.x * wavesPerBlock;

    float acc = 0.0f;

    for (int seg = waveGid; seg < n_segs; seg += totalWaves) {
        const size_t base = (size_t)seg * BIN;
        // lane i owns elements [4i, 4i+4) -> 1 KiB coalesced per array per wave
        const float4 l4 = *reinterpret_cast<const float4*>(logits + base + lane * 4);
        const float4 g4 = *reinterpret_cast<const float4*>(gumbel + base + lane * 4);
        const float z0 = l4.x + g4.x;
        const float z1 = l4.y + g4.y;
        const float z2 = l4.z + g4.z;
        const float z3 = l4.w + g4.w;

        // wave-wide max
        float m = fmaxf(fmaxf(z0, z1), fmaxf(z2, z3));
        #pragma unroll
        for (int off = 1; off < 64; off <<= 1)
            m = fmaxf(m, __shfl_xor(m, off));

        // wave-wide sum of exp(z - m)
        float s = __expf(z0 - m) + __expf(z1 - m) + __expf(z2 - m) + __expf(z3 - m);
        #pragma unroll
        for (int off = 1; off < 64; off <<= 1)
            s += __shfl_xor(s, off);

        const float lse = m + __logf(s);

        const int t = targets[seg];
        if ((t >> 2) == lane) {
            // keep = !mask  -> picked zeroed when mask set
            if (mask[base + t] == 0) {
                const int r = t & 3;
                const float zt = (r == 0) ? z0 : (r == 1) ? z1 : (r == 2) ? z2 : z3;
                acc += (lse - zt);   // -(z_t - lse)
            }
        }
    }

    // wave reduce, then block reduce, one atomic per block
    #pragma unroll
    for (int off = 1; off < 64; off <<= 1)
        acc += __shfl_xor(acc, off);

    __shared__ float waveSums[8];
    if (lane == 0) waveSums[waveInBlock] = acc;
    __syncthreads();
    if (threadIdx.x == 0) {
        float s = 0.0f;
        for (int w = 0; w < wavesPerBlock; ++w) s += waveSums[w];
        atomicAdd(out, s);
    }
}

__global__ void obs_loss_finalize(float* __restrict__ out)
{
    // avg_loss = loss / (B * ln(2))
    out[1] = out[0] * (1.0f / (4096.0f * 0.69314718055994530942f));
}

extern "C" void kernel_launch(void* const* d_in, const int* in_sizes, int n_in,
                              void* d_out, int out_size, void* d_ws, size_t ws_size,
                              hipStream_t stream)
{
    const float* logits = (const float*)d_in[0];
    const float* gumbel = (const float*)d_in[1];
    const int* mask = (const int*)d_in[2];
    const int* targets = (const int*)d_in[3];
    float* out = (float*)d_out;

    const int n_segs = in_sizes[3];   // B * N_COLS = 262144

    // d_out is re-poisoned to 0xAA before every replay — zero it ourselves.
    hipMemsetAsync(out, 0, 2 * sizeof(float), stream);

    const int block = 256;
    const int grid = 2048;            // grid-stride: 32 segments per wave
    obs_loss_kernel<<<grid, block, 0, stream>>>(logits, gumbel, mask, targets, out, n_segs);
    obs_loss_finalize<<<1, 1, 0, stream>>>(out);
}